// Round 1
// baseline (646.684 us; speedup 1.0000x reference)
//
#include <hip/hip_runtime.h>
#include <hip/hip_bf16.h>
#include <hip/hip_fp16.h>

#define N_NODES 50000
#define N_EDGES 1600000
#define HEADS 8
#define HD 32
#define FIN 256
#define HID 256

typedef unsigned short u16;
typedef unsigned int u32;

typedef short s8v __attribute__((ext_vector_type(8)));   // 8 bf16 (4 VGPRs)
typedef float f4v __attribute__((ext_vector_type(4)));   // 4 fp32 acc

// pack 2 fp32 -> 2 bf16 (RNE) in one u32; lowers to v_cvt_pk_bf16_f32 on gfx950
__device__ __forceinline__ u32 pk2(float lo, float hi) {
  __hip_bfloat162 b = __float22bfloat162_rn(make_float2(lo, hi));
  union { __hip_bfloat162 b2; u32 u; } c;
  c.b2 = b;
  return c.u;
}

// ---------------- MFMA GEMM + fused attn projections ------------------------
// H[n][h*32+d] = X[n,:] @ W[h,:,d] + bw[h,d], stored **f16** (better precision
// than bf16 AND enables v_fma_mix_f32 in the gather kernel).
__global__ __launch_bounds__(256) void k_gemm(
    const float* __restrict__ X, const float* __restrict__ W,
    const float* __restrict__ bw, const float* __restrict__ A,
    __half* __restrict__ Hb, float* __restrict__ si, float* __restrict__ sj) {
  __shared__ __align__(16) u16 Xs[128 * 40];  // [row][k] stride 40 (2-way max)
  __shared__ __align__(16) u16 Wt[128 * 40];  // [col][k] stride 40

  const int t = threadIdx.x;
  const int m0 = (blockIdx.x >> 1) * 128;
  const int n0 = (blockIdx.x & 1) * 128;
  const int w = t >> 6;
  const int lane = t & 63;
  const int l15 = lane & 15;
  const int quad = lane >> 4;
  const int wm = (w >> 1) * 64;   // wave row offset in block tile
  const int wn = (w & 1) * 64;    // wave col offset in block tile

  f4v acc[4][4];
#pragma unroll
  for (int i = 0; i < 4; i++)
#pragma unroll
    for (int j = 0; j < 4; j++) acc[i][j] = (f4v){0.f, 0.f, 0.f, 0.f};

  // W staging assignment (constant over k-loop)
  const int nl = t & 127;          // local col
  const int half = t >> 7;         // k half (0/1): kk = half*16 + i
  const int gn = n0 + nl;
  const int gh = gn >> 5, gd = gn & 31;

  for (int k0 = 0; k0 < FIN; k0 += 32) {
    // stage X tile: 128 rows x 32 k (fp32 -> bf16)
#pragma unroll
    for (int p = 0; p < 4; p++) {
      int row = p * 32 + (t >> 3);
      int f4 = t & 7;
      int node = m0 + row;
      float4 xv = make_float4(0.f, 0.f, 0.f, 0.f);
      if (node < N_NODES) xv = *(const float4*)&X[node * FIN + k0 + f4 * 4];
      u32* dst = (u32*)&Xs[row * 40 + f4 * 4];
      dst[0] = pk2(xv.x, xv.y);
      dst[1] = pk2(xv.z, xv.w);
    }
    // stage W tile transposed: Wt[col][kk] = W[h][k0+kk][d]
    {
      const float* wp = W + gh * (FIN * HD) + (k0 + half * 16) * HD + gd;
#pragma unroll
      for (int j = 0; j < 8; j++) {
        float lo = wp[(2 * j) * HD];
        float hi = wp[(2 * j + 1) * HD];
        *(u32*)&Wt[nl * 40 + half * 16 + 2 * j] = pk2(lo, hi);
      }
    }
    __syncthreads();
    s8v af[4], bf[4];
#pragma unroll
    for (int mi = 0; mi < 4; mi++)
      af[mi] = *(const s8v*)&Xs[(wm + mi * 16 + l15) * 40 + quad * 8];
#pragma unroll
    for (int ni = 0; ni < 4; ni++)
      bf[ni] = *(const s8v*)&Wt[(wn + ni * 16 + l15) * 40 + quad * 8];
#pragma unroll
    for (int mi = 0; mi < 4; mi++)
#pragma unroll
      for (int ni = 0; ni < 4; ni++)
        acc[mi][ni] = __builtin_amdgcn_mfma_f32_16x16x32_bf16(af[mi], bf[ni], acc[mi][ni], 0, 0, 0);
    __syncthreads();
  }

  // epilogue: bias, store f16 H, fused si/sj
  const int head0 = (n0 + wn) >> 5;
  const int head1 = head0 + 1;
  float c1a0 = A[head0 * 64 + l15],      c1a1 = A[head0 * 64 + 16 + l15];
  float c2a0 = A[head0 * 64 + 32 + l15], c2a1 = A[head0 * 64 + 48 + l15];
  float c1b0 = A[head1 * 64 + l15],      c1b1 = A[head1 * 64 + 16 + l15];
  float c2b0 = A[head1 * 64 + 32 + l15], c2b1 = A[head1 * 64 + 48 + l15];

#pragma unroll
  for (int mi = 0; mi < 4; mi++) {
    // bias (per-col)
#pragma unroll
    for (int ni = 0; ni < 4; ni++) {
      float b = bw[n0 + wn + ni * 16 + l15];
#pragma unroll
      for (int r = 0; r < 4; r++) acc[mi][ni][r] += b;
    }
    // store H (f16, 1-op cvt)
    const int rbase = m0 + wm + mi * 16 + quad * 4;
#pragma unroll
    for (int r = 0; r < 4; r++) {
      int node = rbase + r;
      if (node < N_NODES) {
#pragma unroll
        for (int ni = 0; ni < 4; ni++) {
          int col = n0 + wn + ni * 16 + l15;
          Hb[node * HID + col] = __float2half_rn(acc[mi][ni][r]);
        }
      }
    }
    // si/sj: dot over head dims via intra-quad shuffle reduce
    float s1a[4], s2a[4], s1b[4], s2b[4];
#pragma unroll
    for (int r = 0; r < 4; r++) {
      s1a[r] = acc[mi][0][r] * c1a0 + acc[mi][1][r] * c1a1;
      s2a[r] = acc[mi][0][r] * c2a0 + acc[mi][1][r] * c2a1;
      s1b[r] = acc[mi][2][r] * c1b0 + acc[mi][3][r] * c1b1;
      s2b[r] = acc[mi][2][r] * c2b0 + acc[mi][3][r] * c2b1;
    }
#pragma unroll
    for (int off = 1; off <= 8; off <<= 1) {
#pragma unroll
      for (int r = 0; r < 4; r++) {
        s1a[r] += __shfl_xor(s1a[r], off);
        s2a[r] += __shfl_xor(s2a[r], off);
        s1b[r] += __shfl_xor(s1b[r], off);
        s2b[r] += __shfl_xor(s2b[r], off);
      }
    }
    if (l15 == 0) {
#pragma unroll
      for (int r = 0; r < 4; r++) {
        int node = rbase + r;
        if (node < N_NODES) {
          si[node * HEADS + head0] = s1a[r];
          sj[node * HEADS + head0] = s2a[r];
          si[node * HEADS + head1] = s1b[r];
          sj[node * HEADS + head1] = s2b[r];
        }
      }
    }
  }
}

// ---------------- counting sort of edges by target ----------------
__global__ void k_hist(const int* __restrict__ tgt, int* __restrict__ cnt) {
  int e = blockIdx.x * 256 + threadIdx.x;
  if (e < N_EDGES) atomicAdd(&cnt[tgt[e]], 1);
}

__global__ __launch_bounds__(256) void k_scan1(const int* __restrict__ cnt,
    int* __restrict__ excl, int* __restrict__ bsum) {
  __shared__ int s[256];
  const int t = threadIdx.x;
  const int i = blockIdx.x * 256 + t;
  int v = (i < N_NODES) ? cnt[i] : 0;
  s[t] = v;
  __syncthreads();
  int x = v;
  for (int off = 1; off < 256; off <<= 1) {
    int y = (t >= off) ? s[t - off] : 0;
    __syncthreads();
    x += y;
    s[t] = x;
    __syncthreads();
  }
  if (i < N_NODES) excl[i] = x - v;
  if (t == 255) bsum[blockIdx.x] = x;
}

// scan2 also transposes Wout (32x256 -> 256x32) -- free ride on the 1-block kernel
__global__ __launch_bounds__(256) void k_scan2(const int* __restrict__ bsum,
                                               int* __restrict__ boff,
                                               const float* __restrict__ Wout,
                                               float* __restrict__ WoutT) {
  __shared__ int s[256];
  const int t = threadIdx.x;
  int v = (t < 196) ? bsum[t] : 0;
  s[t] = v;
  __syncthreads();
  int x = v;
  for (int off = 1; off < 256; off <<= 1) {
    int y = (t >= off) ? s[t - off] : 0;
    __syncthreads();
    x += y;
    s[t] = x;
    __syncthreads();
  }
  if (t < 196) boff[t] = x - v;
#pragma unroll
  for (int k = 0; k < 32; k++) WoutT[t * 32 + k] = Wout[k * HID + t];
}

__global__ void k_scan3(const int* __restrict__ excl, const int* __restrict__ boff,
                        int* __restrict__ rowptr, int* __restrict__ cursor) {
  int i = blockIdx.x * 256 + threadIdx.x;
  if (i < N_NODES) {
    int v = excl[i] + boff[blockIdx.x];
    rowptr[i] = v;
    cursor[i] = v;
  }
}

__global__ void k_scatter(const int* __restrict__ tgt, const int* __restrict__ src,
                          int* __restrict__ cursor, int* __restrict__ sortedSrc) {
  int e = blockIdx.x * 256 + threadIdx.x;
  if (e < N_EDGES) {
    int tg = tgt[e];
    int pos = atomicAdd(&cursor[tg], 1);
    sortedSrc[pos] = src[e];
  }
}

// ---------------- fused: softmax-agg + skip + ELU + LN + head-mean + Wout + ELU
__global__ __launch_bounds__(256) void k_fused(
    const __half* __restrict__ Hb, const float* __restrict__ si,
    const float* __restrict__ sj, const float* __restrict__ ba,
    const float* __restrict__ gamma, const float* __restrict__ beta,
    const float* __restrict__ WoutT, const float* __restrict__ bout,
    const int* __restrict__ rowptr, const int* __restrict__ cnt,
    const int* __restrict__ sortedSrc, float* __restrict__ out) {
  __shared__ __align__(16) float2 exo[32][8];  // {exp(e), Hb-row byte offset}
  __shared__ float sbase[8];                   // si[n,h] + ba[h]
  __shared__ float accs[8][260];               // [edge-slot][col], 260: bank-quad spread
  __shared__ float dens[8][32];                // [edge-slot][col-group]
  __shared__ float lnorm[256];
  __shared__ __align__(16) float meanv[32];

  const int n = blockIdx.x;
  const int t = threadIdx.x;
  const int cg = t & 31;           // col group: cols cg*8 .. cg*8+7
  const int es = t >> 5;           // edge slot 0..7
  const int hh = cg >> 2;          // head of this col group
  const int start = rowptr[n];
  const int deg = cnt[n];
  if (t < 8) sbase[t] = si[n * HEADS + t] + ba[t];
  __syncthreads();

  const int i2c = t >> 3, h8 = t & 7;
  float acc[8] = {0.f, 0.f, 0.f, 0.f, 0.f, 0.f, 0.f, 0.f};
  float den = 0.f;
  for (int base = 0; base < deg; base += 32) {
    const int m = min(32, deg - base);
    {
      float exv = 0.f;
      u32 off0 = 0;
      if (i2c < m) {
        int s = sortedSrc[start + base + i2c];
        float e = sbase[h8] + sj[s * HEADS + h8];
        e = (e >= 0.f) ? e : 0.2f * e;
        exv = __expf(e);
        off0 = (u32)s * (HID * 2);
      }
      exo[i2c][h8] = make_float2(exv, __uint_as_float(off0));
    }
    __syncthreads();
#pragma unroll
    for (int k = 0; k < 4; k++) {
      float2 eo = exo[k * 8 + es][hh];            // one ds_read_b64
      float exv = eo.x;
      u32 off = __float_as_uint(eo.y);
      float4 hb4 = *(const float4*)((const char*)Hb + off + 16 * cg);
      const __half2* hp = (const __half2*)&hb4;
#pragma unroll
      for (int d = 0; d < 4; d++) {
        // fma(fpext(f16), f32, f32) -> v_fma_mix_f32 (no unpack ops)
        acc[2 * d]     += exv * __low2float(hp[d]);
        acc[2 * d + 1] += exv * __high2float(hp[d]);
      }
      den += exv;
    }
    __syncthreads();
  }
#pragma unroll
  for (int j = 0; j < 8; j++) accs[es][cg * 8 + j] = acc[j];
  dens[es][cg] = den;
  __syncthreads();

  float accT = 0.f, denT = 0.f;
#pragma unroll
  for (int e2 = 0; e2 < 8; e2++) {
    accT += accs[e2][t];
    denT += dens[e2][t >> 3];
  }
  float hs = __half2float(Hb[n * HID + t]);
  float v = ((deg > 0) ? __fdividef(accT, denT) : 0.f) + hs;
  v = (v > 0.f) ? v : (__expf(v) - 1.f);        // fast ELU
  float sum = v, sq = v * v;
#pragma unroll
  for (int off = 16; off >= 1; off >>= 1) {
    sum += __shfl_xor(sum, off);
    sq  += __shfl_xor(sq, off);
  }
  float mu = sum * (1.f / 32.f);
  float var = sq * (1.f / 32.f) - mu * mu;
  float nv = (v - mu) * rsqrtf(var + 1e-5f) * gamma[t] + beta[t];
  lnorm[t] = nv;
  __syncthreads();
  if (t < 32) {
    float m2 = 0.f;
#pragma unroll
    for (int h2 = 0; h2 < HEADS; h2++) m2 += lnorm[h2 * 32 + t];
    meanv[t] = m2 * 0.125f;
  }
  __syncthreads();
  float y = bout[t];
  const float4* wt = (const float4*)&WoutT[t * 32];
#pragma unroll
  for (int q = 0; q < 8; q++) {
    float4 wv = wt[q];                           // 8 dwordx4 instead of 32 dwords
    float4 mq = *(const float4*)&meanv[4 * q];   // ds_read_b128 broadcast
    y += mq.x * wv.x + mq.y * wv.y + mq.z * wv.z + mq.w * wv.w;
  }
  y = (y > 0.f) ? y : (__expf(y) - 1.f);        // fast ELU
  out[n * HID + t] = y;
}

extern "C" void kernel_launch(void* const* d_in, const int* in_sizes, int n_in,
                              void* d_out, int out_size, void* d_ws, size_t ws_size,
                              hipStream_t stream) {
  const float* X     = (const float*)d_in[0];
  const int*   EI    = (const int*)d_in[1];
  const float* W     = (const float*)d_in[2];
  const float* bw    = (const float*)d_in[3];
  const float* A     = (const float*)d_in[4];
  const float* ba    = (const float*)d_in[5];
  const float* gamma = (const float*)d_in[6];
  const float* beta  = (const float*)d_in[7];
  const float* Wout  = (const float*)d_in[8];
  const float* bout  = (const float*)d_in[9];
  float* out = (float*)d_out;
  const int* tgt = EI;
  const int* src = EI + N_EDGES;

  char* ws = (char*)d_ws;
  size_t off = 0;
  auto alloc = [&](size_t bytes) -> void* {
    void* p = ws + off;
    off += bytes;
    off = (off + 255) & ~(size_t)255;
    return p;
  };
  __half* Hb       = (__half*)alloc((size_t)N_NODES * HID * 2);
  float* si        = (float*)alloc((size_t)N_NODES * HEADS * 4);
  float* sj        = (float*)alloc((size_t)N_NODES * HEADS * 4);
  int*   cnt       = (int*)  alloc((size_t)N_NODES * 4);
  int*   excl      = (int*)  alloc((size_t)N_NODES * 4);
  int*   bsum      = (int*)  alloc(256 * 4);
  int*   boff      = (int*)  alloc(256 * 4);
  int*   rowptr    = (int*)  alloc((size_t)N_NODES * 4);
  int*   cursor    = (int*)  alloc((size_t)N_NODES * 4);
  int*   sortedSrc = (int*)  alloc((size_t)N_EDGES * 4);
  float* WoutT     = (float*)alloc((size_t)HID * HD * 4);

  hipMemsetAsync(cnt, 0, (size_t)N_NODES * 4, stream);
  k_hist<<<(N_EDGES + 255) / 256, 256, 0, stream>>>(tgt, cnt);
  k_scan1<<<196, 256, 0, stream>>>(cnt, excl, bsum);
  k_scan2<<<1, 256, 0, stream>>>(bsum, boff, Wout, WoutT);
  k_scan3<<<196, 256, 0, stream>>>(excl, boff, rowptr, cursor);
  k_scatter<<<(N_EDGES + 255) / 256, 256, 0, stream>>>(tgt, src, cursor, sortedSrc);
  k_gemm<<<((N_NODES + 127) / 128) * 2, 256, 0, stream>>>(X, W, bw, A, Hb, si, sj);
  k_fused<<<N_NODES, 256, 0, stream>>>(Hb, si, sj, ba, gamma, beta, WoutT, bout,
                                       rowptr, cnt, sortedSrc, out);
}

// Round 2
// 522.352 us; speedup vs baseline: 1.2380x; 1.2380x over previous
//
#include <hip/hip_runtime.h>
#include <hip/hip_bf16.h>
#include <hip/hip_fp16.h>

#define N_NODES 50000
#define N_EDGES 1600000
#define HEADS 8
#define HD 32
#define FIN 256
#define HID 256

typedef unsigned short u16;
typedef unsigned int u32;

typedef short s8v __attribute__((ext_vector_type(8)));   // 8 bf16 (4 VGPRs)
typedef float f4v __attribute__((ext_vector_type(4)));   // 4 fp32 acc

// pack 2 fp32 -> 2 bf16 (RNE) in one u32; lowers to v_cvt_pk_bf16_f32 on gfx950
__device__ __forceinline__ u32 pk2(float lo, float hi) {
  __hip_bfloat162 b = __float22bfloat162_rn(make_float2(lo, hi));
  union { __hip_bfloat162 b2; u32 u; } c;
  c.b2 = b;
  return c.u;
}

// ---------------- MFMA GEMM + fused attn projections ------------------------
// H[n][h*32+d] = X[n,:] @ W[h,:,d] + bw[h,d], stored **f16** (better precision
// than bf16 AND enables v_fma_mix_f32 in the gather kernel).
__global__ __launch_bounds__(256) void k_gemm(
    const float* __restrict__ X, const float* __restrict__ W,
    const float* __restrict__ bw, const float* __restrict__ A,
    __half* __restrict__ Hb, float* __restrict__ si, float* __restrict__ sj) {
  __shared__ __align__(16) u16 Xs[128 * 40];  // [row][k] stride 40 (2-way max)
  __shared__ __align__(16) u16 Wt[128 * 40];  // [col][k] stride 40

  const int t = threadIdx.x;
  const int m0 = (blockIdx.x >> 1) * 128;
  const int n0 = (blockIdx.x & 1) * 128;
  const int w = t >> 6;
  const int lane = t & 63;
  const int l15 = lane & 15;
  const int quad = lane >> 4;
  const int wm = (w >> 1) * 64;   // wave row offset in block tile
  const int wn = (w & 1) * 64;    // wave col offset in block tile

  f4v acc[4][4];
#pragma unroll
  for (int i = 0; i < 4; i++)
#pragma unroll
    for (int j = 0; j < 4; j++) acc[i][j] = (f4v){0.f, 0.f, 0.f, 0.f};

  // W staging assignment (constant over k-loop)
  const int nl = t & 127;          // local col
  const int half = t >> 7;         // k half (0/1): kk = half*16 + i
  const int gn = n0 + nl;
  const int gh = gn >> 5, gd = gn & 31;

  for (int k0 = 0; k0 < FIN; k0 += 32) {
    // stage X tile: 128 rows x 32 k (fp32 -> bf16)
#pragma unroll
    for (int p = 0; p < 4; p++) {
      int row = p * 32 + (t >> 3);
      int f4 = t & 7;
      int node = m0 + row;
      float4 xv = make_float4(0.f, 0.f, 0.f, 0.f);
      if (node < N_NODES) xv = *(const float4*)&X[node * FIN + k0 + f4 * 4];
      u32* dst = (u32*)&Xs[row * 40 + f4 * 4];
      dst[0] = pk2(xv.x, xv.y);
      dst[1] = pk2(xv.z, xv.w);
    }
    // stage W tile transposed: Wt[col][kk] = W[h][k0+kk][d]
    {
      const float* wp = W + gh * (FIN * HD) + (k0 + half * 16) * HD + gd;
#pragma unroll
      for (int j = 0; j < 8; j++) {
        float lo = wp[(2 * j) * HD];
        float hi = wp[(2 * j + 1) * HD];
        *(u32*)&Wt[nl * 40 + half * 16 + 2 * j] = pk2(lo, hi);
      }
    }
    __syncthreads();
    s8v af[4], bf[4];
#pragma unroll
    for (int mi = 0; mi < 4; mi++)
      af[mi] = *(const s8v*)&Xs[(wm + mi * 16 + l15) * 40 + quad * 8];
#pragma unroll
    for (int ni = 0; ni < 4; ni++)
      bf[ni] = *(const s8v*)&Wt[(wn + ni * 16 + l15) * 40 + quad * 8];
#pragma unroll
    for (int mi = 0; mi < 4; mi++)
#pragma unroll
      for (int ni = 0; ni < 4; ni++)
        acc[mi][ni] = __builtin_amdgcn_mfma_f32_16x16x32_bf16(af[mi], bf[ni], acc[mi][ni], 0, 0, 0);
    __syncthreads();
  }

  // epilogue: bias, store f16 H, fused si/sj
  const int head0 = (n0 + wn) >> 5;
  const int head1 = head0 + 1;
  float c1a0 = A[head0 * 64 + l15],      c1a1 = A[head0 * 64 + 16 + l15];
  float c2a0 = A[head0 * 64 + 32 + l15], c2a1 = A[head0 * 64 + 48 + l15];
  float c1b0 = A[head1 * 64 + l15],      c1b1 = A[head1 * 64 + 16 + l15];
  float c2b0 = A[head1 * 64 + 32 + l15], c2b1 = A[head1 * 64 + 48 + l15];

#pragma unroll
  for (int mi = 0; mi < 4; mi++) {
    // bias (per-col)
#pragma unroll
    for (int ni = 0; ni < 4; ni++) {
      float b = bw[n0 + wn + ni * 16 + l15];
#pragma unroll
      for (int r = 0; r < 4; r++) acc[mi][ni][r] += b;
    }
    // store H (f16, 1-op cvt)
    const int rbase = m0 + wm + mi * 16 + quad * 4;
#pragma unroll
    for (int r = 0; r < 4; r++) {
      int node = rbase + r;
      if (node < N_NODES) {
#pragma unroll
        for (int ni = 0; ni < 4; ni++) {
          int col = n0 + wn + ni * 16 + l15;
          Hb[node * HID + col] = __float2half_rn(acc[mi][ni][r]);
        }
      }
    }
    // si/sj: dot over head dims via intra-quad shuffle reduce
    float s1a[4], s2a[4], s1b[4], s2b[4];
#pragma unroll
    for (int r = 0; r < 4; r++) {
      s1a[r] = acc[mi][0][r] * c1a0 + acc[mi][1][r] * c1a1;
      s2a[r] = acc[mi][0][r] * c2a0 + acc[mi][1][r] * c2a1;
      s1b[r] = acc[mi][2][r] * c1b0 + acc[mi][3][r] * c1b1;
      s2b[r] = acc[mi][2][r] * c2b0 + acc[mi][3][r] * c2b1;
    }
#pragma unroll
    for (int off = 1; off <= 8; off <<= 1) {
#pragma unroll
      for (int r = 0; r < 4; r++) {
        s1a[r] += __shfl_xor(s1a[r], off);
        s2a[r] += __shfl_xor(s2a[r], off);
        s1b[r] += __shfl_xor(s1b[r], off);
        s2b[r] += __shfl_xor(s2b[r], off);
      }
    }
    if (l15 == 0) {
#pragma unroll
      for (int r = 0; r < 4; r++) {
        int node = rbase + r;
        if (node < N_NODES) {
          si[node * HEADS + head0] = s1a[r];
          sj[node * HEADS + head0] = s2a[r];
          si[node * HEADS + head1] = s1b[r];
          sj[node * HEADS + head1] = s2b[r];
        }
      }
    }
  }
}

// ---------------- counting sort of edges by target ----------------
__global__ void k_hist(const int* __restrict__ tgt, int* __restrict__ cnt) {
  int e = blockIdx.x * 256 + threadIdx.x;
  if (e < N_EDGES) atomicAdd(&cnt[tgt[e]], 1);
}

__global__ __launch_bounds__(256) void k_scan1(const int* __restrict__ cnt,
    int* __restrict__ excl, int* __restrict__ bsum) {
  __shared__ int s[256];
  const int t = threadIdx.x;
  const int i = blockIdx.x * 256 + t;
  int v = (i < N_NODES) ? cnt[i] : 0;
  s[t] = v;
  __syncthreads();
  int x = v;
  for (int off = 1; off < 256; off <<= 1) {
    int y = (t >= off) ? s[t - off] : 0;
    __syncthreads();
    x += y;
    s[t] = x;
    __syncthreads();
  }
  if (i < N_NODES) excl[i] = x - v;
  if (t == 255) bsum[blockIdx.x] = x;
}

__global__ __launch_bounds__(256) void k_scan2(const int* __restrict__ bsum,
                                               int* __restrict__ boff) {
  __shared__ int s[256];
  const int t = threadIdx.x;
  int v = (t < 196) ? bsum[t] : 0;
  s[t] = v;
  __syncthreads();
  int x = v;
  for (int off = 1; off < 256; off <<= 1) {
    int y = (t >= off) ? s[t - off] : 0;
    __syncthreads();
    x += y;
    s[t] = x;
    __syncthreads();
  }
  if (t < 196) boff[t] = x - v;
}

__global__ void k_scan3(const int* __restrict__ excl, const int* __restrict__ boff,
                        int* __restrict__ rowptr, int* __restrict__ cursor) {
  int i = blockIdx.x * 256 + threadIdx.x;
  if (i < N_NODES) {
    int v = excl[i] + boff[blockIdx.x];
    rowptr[i] = v;
    cursor[i] = v;
  }
}

__global__ void k_scatter(const int* __restrict__ tgt, const int* __restrict__ src,
                          int* __restrict__ cursor, int* __restrict__ sortedSrc) {
  int e = blockIdx.x * 256 + threadIdx.x;
  if (e < N_EDGES) {
    int tg = tgt[e];
    int pos = atomicAdd(&cursor[tg], 1);
    sortedSrc[pos] = src[e];
  }
}

// ---------------- fused: softmax-agg + skip + ELU + LN + head-mean + Wout + ELU
__global__ __launch_bounds__(256) void k_fused(
    const __half* __restrict__ Hb, const float* __restrict__ si,
    const float* __restrict__ sj, const float* __restrict__ ba,
    const float* __restrict__ gamma, const float* __restrict__ beta,
    const float* __restrict__ Wout, const float* __restrict__ bout,
    const int* __restrict__ rowptr, const int* __restrict__ cnt,
    const int* __restrict__ sortedSrc, float* __restrict__ out) {
  __shared__ __align__(16) float2 exo[32][8];  // {exp(e), Hb-row byte offset}
  __shared__ float sbase[8];                   // si[n,h] + ba[h]
  __shared__ float accs[8][260];               // [edge-slot][col], 260: bank-quad spread
  __shared__ float dens[8][32];                // [edge-slot][col-group]
  __shared__ float lnorm[256];
  __shared__ __align__(16) float meanv[32];

  const int n = blockIdx.x;
  const int t = threadIdx.x;
  const int cg = t & 31;           // col group: cols cg*8 .. cg*8+7
  const int es = t >> 5;           // edge slot 0..7
  const int hh = cg >> 2;          // head of this col group
  const int start = rowptr[n];
  const int deg = cnt[n];
  if (t < 8) sbase[t] = si[n * HEADS + t] + ba[t];
  __syncthreads();

  const int i2c = t >> 3, h8 = t & 7;
  const char* hbBase = (const char*)Hb + 16 * cg;   // loop-invariant gather base
  const int* ssBase = sortedSrc + start;
  float acc[8] = {0.f, 0.f, 0.f, 0.f, 0.f, 0.f, 0.f, 0.f};
  float den = 0.f;
  for (int base = 0; base < deg; base += 32) {
    const int m = min(32, deg - base);
    {
      float exv = 0.f;
      u32 off0 = 0;
      if (i2c < m) {
        int s = ssBase[base + i2c];
        float e = sbase[h8] + sj[s * HEADS + h8];
        e = (e >= 0.f) ? e : 0.2f * e;
        exv = __expf(e);
        off0 = (u32)s * (HID * 2);
      }
      exo[i2c][h8] = make_float2(exv, __uint_as_float(off0));
    }
    __syncthreads();
#pragma unroll
    for (int k = 0; k < 4; k++) {
      float2 eo = exo[k * 8 + es][hh];            // one ds_read_b64
      float exv = eo.x;
      u32 off = __float_as_uint(eo.y);
      float4 hb4 = *(const float4*)(hbBase + off);
      const __half2* hp = (const __half2*)&hb4;
#pragma unroll
      for (int d = 0; d < 4; d++) {
        // fma(fpext(f16), f32, f32) -> v_fma_mix_f32 (no unpack ops)
        acc[2 * d]     += exv * __low2float(hp[d]);
        acc[2 * d + 1] += exv * __high2float(hp[d]);
      }
      den += exv;
    }
    __syncthreads();
  }
#pragma unroll
  for (int j = 0; j < 8; j++) accs[es][cg * 8 + j] = acc[j];
  dens[es][cg] = den;
  __syncthreads();

  float accT = 0.f, denT = 0.f;
#pragma unroll
  for (int e2 = 0; e2 < 8; e2++) {
    accT += accs[e2][t];
    denT += dens[e2][t >> 3];
  }
  float hs = __half2float(Hb[n * HID + t]);
  float v = ((deg > 0) ? __fdividef(accT, denT) : 0.f) + hs;
  v = (v > 0.f) ? v : (__expf(v) - 1.f);        // fast ELU
  float sum = v, sq = v * v;
#pragma unroll
  for (int off = 16; off >= 1; off >>= 1) {
    sum += __shfl_xor(sum, off);
    sq  += __shfl_xor(sq, off);
  }
  float mu = sum * (1.f / 32.f);
  float var = sq * (1.f / 32.f) - mu * mu;
  float nv = (v - mu) * rsqrtf(var + 1e-5f) * gamma[t] + beta[t];
  lnorm[t] = nv;
  __syncthreads();
  if (t < 32) {
    float m2 = 0.f;
#pragma unroll
    for (int h2 = 0; h2 < HEADS; h2++) m2 += lnorm[h2 * 32 + t];
    meanv[t] = m2 * 0.125f;
  }
  __syncthreads();
  // Output projection: coalesced dword loads (lane-consecutive addresses).
  // NOTE: do NOT transpose Wout for per-thread-contiguous float4 loads — that
  // puts lanes 128 B apart (64 L1 lines per wave instr) and cost +125 us in R1.
  float y = bout[t];
#pragma unroll
  for (int k = 0; k < 32; k++) y += meanv[k] * Wout[k * HID + t];
  y = (y > 0.f) ? y : (__expf(y) - 1.f);        // fast ELU
  out[n * HID + t] = y;
}

extern "C" void kernel_launch(void* const* d_in, const int* in_sizes, int n_in,
                              void* d_out, int out_size, void* d_ws, size_t ws_size,
                              hipStream_t stream) {
  const float* X     = (const float*)d_in[0];
  const int*   EI    = (const int*)d_in[1];
  const float* W     = (const float*)d_in[2];
  const float* bw    = (const float*)d_in[3];
  const float* A     = (const float*)d_in[4];
  const float* ba    = (const float*)d_in[5];
  const float* gamma = (const float*)d_in[6];
  const float* beta  = (const float*)d_in[7];
  const float* Wout  = (const float*)d_in[8];
  const float* bout  = (const float*)d_in[9];
  float* out = (float*)d_out;
  const int* tgt = EI;
  const int* src = EI + N_EDGES;

  char* ws = (char*)d_ws;
  size_t off = 0;
  auto alloc = [&](size_t bytes) -> void* {
    void* p = ws + off;
    off += bytes;
    off = (off + 255) & ~(size_t)255;
    return p;
  };
  __half* Hb       = (__half*)alloc((size_t)N_NODES * HID * 2);
  float* si        = (float*)alloc((size_t)N_NODES * HEADS * 4);
  float* sj        = (float*)alloc((size_t)N_NODES * HEADS * 4);
  int*   cnt       = (int*)  alloc((size_t)N_NODES * 4);
  int*   excl      = (int*)  alloc((size_t)N_NODES * 4);
  int*   bsum      = (int*)  alloc(256 * 4);
  int*   boff      = (int*)  alloc(256 * 4);
  int*   rowptr    = (int*)  alloc((size_t)N_NODES * 4);
  int*   cursor    = (int*)  alloc((size_t)N_NODES * 4);
  int*   sortedSrc = (int*)  alloc((size_t)N_EDGES * 4);

  hipMemsetAsync(cnt, 0, (size_t)N_NODES * 4, stream);
  k_hist<<<(N_EDGES + 255) / 256, 256, 0, stream>>>(tgt, cnt);
  k_scan1<<<196, 256, 0, stream>>>(cnt, excl, bsum);
  k_scan2<<<1, 256, 0, stream>>>(bsum, boff);
  k_scan3<<<196, 256, 0, stream>>>(excl, boff, rowptr, cursor);
  k_scatter<<<(N_EDGES + 255) / 256, 256, 0, stream>>>(tgt, src, cursor, sortedSrc);
  k_gemm<<<((N_NODES + 127) / 128) * 2, 256, 0, stream>>>(X, W, bw, A, Hb, si, sj);
  k_fused<<<N_NODES, 256, 0, stream>>>(Hb, si, sj, ba, gamma, beta, Wout, bout,
                                       rowptr, cnt, sortedSrc, out);
}